// Round 24
// baseline (283.108 us; speedup 1.0000x reference)
//
#include <hip/hip_runtime.h>
#include <hip/hip_bf16.h>
#include <hip/hip_fp16.h>
#include <cstdio>

#define B_  64
#define I_  2048
#define J_  16
#define N_  64
#define D_  16
#define K_  1024   // N_*D_

using short8 = __attribute__((ext_vector_type(8))) short;
using f32x16 = __attribute__((ext_vector_type(16))) float;

#if __has_builtin(__builtin_amdgcn_cvt_pk_u8_f32)
#define CVTPK_U8(f, sel, old) (unsigned)__builtin_amdgcn_cvt_pk_u8_f32((f), (sel), (old))
#else
__device__ __forceinline__ unsigned cvtpk_u8_sw(float f, unsigned sel, unsigned old) {
  unsigned b = (unsigned)(int)f & 0xffu;
  unsigned sh = sel * 8u;
  return (old & ~(0xffu << sh)) | (b << sh);
}
#define CVTPK_U8(f, sel, old) cvtpk_u8_sw((f), (sel), (old))
#endif

__device__ __forceinline__ short8 pack_bf16x8(float a0, float a1, float a2, float a3,
                                              float a4, float a5, float a6, float a7) {
  __hip_bfloat162 p0 = __float22bfloat162_rn(float2{a0, a1});
  __hip_bfloat162 p1 = __float22bfloat162_rn(float2{a2, a3});
  __hip_bfloat162 p2 = __float22bfloat162_rn(float2{a4, a5});
  __hip_bfloat162 p3 = __float22bfloat162_rn(float2{a6, a7});
  union { unsigned u[4]; short8 s; } cv;
  cv.u[0] = *(unsigned*)&p0; cv.u[1] = *(unsigned*)&p1;
  cv.u[2] = *(unsigned*)&p2; cv.u[3] = *(unsigned*)&p3;
  return cv.s;
}

// ---------- projection via MFMA 32x32x16, ONE k-quarter per block ----------
// ROUND-22 kernel exactly (best measured: 88.5 us project, no spills at lb(256,5);
// round-23 showed lb(256,8) forces VGPR 32 -> scratch spill +115MB traffic).
// Grid 8192: block = (i = bid>>2, ph = bid&3). LDS aliased 19.2 KB; pad-65 rows.
//   A frag: lane l = A[row=l&31][kappa=(l>>5)*8+e] -> W[j=kappa][k]
//   B frag: lane l = B[kappa=(l>>5)*8+e][col=l&31] -> x[b=col(+32)][j=kappa]
//   D frag: col=l&31 (b), row=(reg&3)+8*(reg>>2)+4*(l>>5)  [m74/m101-verified]
__global__ __launch_bounds__(256, 5) void project_k(const float* __restrict__ x,
                                                    const float* __restrict__ W,
                                                    unsigned char* __restrict__ uh,
                                                    unsigned short* __restrict__ sc,
                                                    float* __restrict__ s_zero,
                                                    unsigned* __restrict__ ctr) {
  const int i  = blockIdx.x >> 2;
  const int ph = blockIdx.x & 3;
  const int t  = threadIdx.x;
  const int l  = t & 63;
  const int wv = t >> 6;
  const int h  = l >> 5;
  const int lr = l & 31;

  __shared__ __align__(16) char smem[19200];
  unsigned short* lds_w   = (unsigned short*)smem;           // [256*20] 10240 B
  float*          lds_x   = (float*)(smem + 10240);          // [64*20]   5120 B
  unsigned*       out_lds = (unsigned*)smem;                 // [64*65]  16640 B (aliases stage)
  unsigned short* sc_lds  = (unsigned short*)(smem + 16640); // [64*20]   2560 B

  if (blockIdx.x < 768) s_zero[blockIdx.x * 256 + t] = 0.f;  // replaces memset
  if (blockIdx.x == 0 && t == 0) ctr[0] = 0u;                // tail-squash counter

  {
    int b = t >> 2, q = t & 3;
    float4 v = ((const float4*)(x + ((size_t)b * I_ + i) * J_))[q];
    *(float4*)&lds_x[b * 20 + q * 4] = v;
  }
  {
    const float* wp = W + (size_t)i * (J_ * K_) + ph * 256;
    const int j0 = (t & 3) * 4;
    const int kg = t >> 2;
    float4 r0 = *(const float4*)(wp + (size_t)(j0 + 0) * K_ + kg * 4);
    float4 r1 = *(const float4*)(wp + (size_t)(j0 + 1) * K_ + kg * 4);
    float4 r2 = *(const float4*)(wp + (size_t)(j0 + 2) * K_ + kg * 4);
    float4 r3 = *(const float4*)(wp + (size_t)(j0 + 3) * K_ + kg * 4);
    const float* p0 = (const float*)&r0;
    const float* p1 = (const float*)&r1;
    const float* p2 = (const float*)&r2;
    const float* p3 = (const float*)&r3;
#pragma unroll
    for (int kk = 0; kk < 4; ++kk) {
      __hip_bfloat162 pA = __float22bfloat162_rn(float2{p0[kk], p1[kk]});
      __hip_bfloat162 pB = __float22bfloat162_rn(float2{p2[kk], p3[kk]});
      uint2 u; u.x = *(unsigned*)&pA; u.y = *(unsigned*)&pB;
      *(uint2*)&lds_w[(kg * 4 + kk) * 20 + j0] = u;
    }
  }
  __syncthreads();

  short8 xfrag;
  {
    int b = (wv & 1) * 32 + lr;
    const float* xp = &lds_x[b * 20 + h * 8];
    float4 f0 = *(const float4*)xp;
    float4 f1 = *(const float4*)(xp + 4);
    xfrag = pack_bf16x8(f0.x, f0.y, f0.z, f0.w, f1.x, f1.y, f1.z, f1.w);
  }

  const int b  = (wv & 1) * 32 + lr;
  const int kt_base = (wv >> 1) * 4;

  unsigned pkr[16];
  float    axr[8];

#pragma unroll
  for (int kk = 0; kk < 4; ++kk) {
    const int kt = kt_base + kk;
    const unsigned short* ap = &lds_w[(kt * 32 + lr) * 20 + h * 8];
    union { uint2 u2[2]; short8 s; } cv;
    cv.u2[0] = *(const uint2*)ap;
    cv.u2[1] = *(const uint2*)(ap + 4);
    f32x16 acc = {0.f, 0.f, 0.f, 0.f, 0.f, 0.f, 0.f, 0.f,
                  0.f, 0.f, 0.f, 0.f, 0.f, 0.f, 0.f, 0.f};
    acc = __builtin_amdgcn_mfma_f32_32x32x16_bf16(cv.s, xfrag, acc, 0, 0, 0);

#define QCAP(C8, CS) do {                                                       \
    float ax = fabsf(acc[(C8) + 0]);                                            \
    ax = fmaxf(ax, fabsf(acc[(C8) + 1]));                                       \
    ax = fmaxf(ax, fabsf(acc[(C8) + 2]));                                       \
    ax = fmaxf(ax, fabsf(acc[(C8) + 3]));                                       \
    ax = fmaxf(ax, fabsf(acc[(C8) + 4]));                                       \
    ax = fmaxf(ax, fabsf(acc[(C8) + 5]));                                       \
    ax = fmaxf(ax, fabsf(acc[(C8) + 6]));                                       \
    ax = fmaxf(ax, fabsf(acc[(C8) + 7]));                                       \
    ax = fmaxf(ax, __shfl_xor(ax, 32));                                         \
    float inv = __fdividef(127.0f, fmaxf(ax, 1e-30f));                          \
    unsigned pk0 = CVTPK_U8(rintf(fmaf(acc[(C8) + 0], inv, 128.f)), 0u, 0u);    \
    pk0 = CVTPK_U8(rintf(fmaf(acc[(C8) + 1], inv, 128.f)), 1u, pk0);            \
    pk0 = CVTPK_U8(rintf(fmaf(acc[(C8) + 2], inv, 128.f)), 2u, pk0);            \
    pk0 = CVTPK_U8(rintf(fmaf(acc[(C8) + 3], inv, 128.f)), 3u, pk0);            \
    unsigned pk1 = CVTPK_U8(rintf(fmaf(acc[(C8) + 4], inv, 128.f)), 0u, 0u);    \
    pk1 = CVTPK_U8(rintf(fmaf(acc[(C8) + 5], inv, 128.f)), 1u, pk1);            \
    pk1 = CVTPK_U8(rintf(fmaf(acc[(C8) + 6], inv, 128.f)), 2u, pk1);            \
    pk1 = CVTPK_U8(rintf(fmaf(acc[(C8) + 7], inv, 128.f)), 3u, pk1);            \
    pkr[kk * 4 + (CS) * 2 + 0] = pk0;                                           \
    pkr[kk * 4 + (CS) * 2 + 1] = pk1;                                           \
    axr[kk * 2 + (CS)] = ax;                                                    \
  } while (0)

    QCAP(0, 0);
    QCAP(8, 1);
#undef QCAP
  }
  __syncthreads();   // stage region dead; out region live

#pragma unroll
  for (int kk = 0; kk < 4; ++kk) {
    const int kt = kt_base + kk;
#pragma unroll
    for (int cs = 0; cs < 2; ++cs) {
      const int ibase = kt * 8 + cs * 4;
      out_lds[b * 65 + ibase + h]     = pkr[kk * 4 + cs * 2 + 0];
      out_lds[b * 65 + ibase + 2 + h] = pkr[kk * 4 + cs * 2 + 1];
      if (h == 0)
        sc_lds[b * 20 + kt * 2 + cs] =
            __half_as_ushort(__float2half_rn(axr[kk * 2 + cs] * (1.0f / 127.0f)));
    }
  }
  __syncthreads();

  {
    const int c = t & 15;
#pragma unroll
    for (int it = 0; it < 4; ++it) {
      int bf = (t >> 4) + it * 16;
      const unsigned* rp = &out_lds[bf * 65 + c * 4];
      uint4 v;
      v.x = rp[0]; v.y = rp[1]; v.z = rp[2]; v.w = rp[3];
      *(uint4*)(uh + (size_t)bf * I_ * K_ + (size_t)i * K_ + ph * 256 + c * 16) = v;
    }
    int b2 = t >> 2, n4 = (t & 3) * 4;
    uint2 sv = *(const uint2*)&sc_lds[b2 * 20 + n4];
    *(uint2*)(sc + (size_t)b2 * I_ * N_ + (size_t)i * N_ + ph * 16 + n4) = sv;
  }
}

// ---------- routing on u8 u_hat (e = q+128): lane = n; 16 B data + 2 B scale ----------
// MODE 2 additionally FUSES squash: last-finishing block (device-fence + counter)
// computes out = squash(s2 + bias) for all 64 batches — removes the squash
// dispatch and one inter-kernel gap. Deterministic: last block reads complete s2.
template <int MODE>
__global__ __launch_bounds__(256, 4) void route_k(const unsigned char* __restrict__ uh,
                                                  const unsigned short* __restrict__ sc,
                                                  const float* __restrict__ sa,
                                                  const float* __restrict__ sb,
                                                  const float* __restrict__ bias,
                                                  float* __restrict__ s_out,
                                                  unsigned* __restrict__ ctr,
                                                  float* __restrict__ out) {
  const int t    = threadIdx.x;
  const int lane = t & 63;            // = n
  const int wv   = t >> 6;            // 0..3
  const int b    = blockIdx.x >> 4;
  const int iw   = ((blockIdx.x & 15) << 2) + wv;
  const int i0   = iw * 32;

  float vsum[16];
  float voff = 0.f;
  if (MODE >= 1) {
    float bs[16];
#pragma unroll
    for (int q = 0; q < 4; ++q) {
      float4 bb4 = *(const float4*)&bias[lane * 16 + q * 4];
      bs[q*4+0] = bb4.x; bs[q*4+1] = bb4.y; bs[q*4+2] = bb4.z; bs[q*4+3] = bb4.w;
    }
    {
      float va[16], nn = 0.f;
#pragma unroll
      for (int q = 0; q < 4; ++q) {
        float4 tmp = *(const float4*)&sa[(size_t)b * K_ + lane * 16 + q * 4];
        va[q*4+0] = tmp.x + bs[q*4+0]; va[q*4+1] = tmp.y + bs[q*4+1];
        va[q*4+2] = tmp.z + bs[q*4+2]; va[q*4+3] = tmp.w + bs[q*4+3];
      }
#pragma unroll
      for (int d = 0; d < 16; ++d) nn += va[d] * va[d];
      float n2 = nn + 1e-7f;
      float f = sqrtf(n2) / (1.0f + n2);
#pragma unroll
      for (int d = 0; d < 16; ++d) vsum[d] = va[d] * f;
    }
    if (MODE == 2) {
      float vb[16], nn = 0.f;
#pragma unroll
      for (int q = 0; q < 4; ++q) {
        float4 tmp = *(const float4*)&sb[(size_t)b * K_ + lane * 16 + q * 4];
        vb[q*4+0] = tmp.x + bs[q*4+0]; vb[q*4+1] = tmp.y + bs[q*4+1];
        vb[q*4+2] = tmp.z + bs[q*4+2]; vb[q*4+3] = tmp.w + bs[q*4+3];
      }
#pragma unroll
      for (int d = 0; d < 16; ++d) nn += vb[d] * vb[d];
      float n2 = nn + 1e-7f;
      float f = sqrtf(n2) / (1.0f + n2);
#pragma unroll
      for (int d = 0; d < 16; ++d) vsum[d] += vb[d] * f;
    }
    float tv = 0.f;
#pragma unroll
    for (int d = 0; d < 16; ++d) tv += vsum[d];
    voff = 128.0f * tv;
  }

  constexpr int IPW = 32;
  constexpr int PF  = 4;

  const unsigned char*  base = uh + (size_t)b * I_ * K_ + lane * 16;
  const unsigned short* scb  = sc + (size_t)b * I_ * N_ + lane;

  uint4 dbuf[PF];
  unsigned short hbuf[PF];
#pragma unroll
  for (int p = 0; p < PF; ++p) {
    int ip = (i0 + p) & (I_ - 1);
    dbuf[p] = *(const uint4*)(base + (size_t)ip * K_);
    hbuf[p] = scb[(size_t)ip * N_];
  }

  float s_loc[16];
#pragma unroll
  for (int d = 0; d < 16; ++d) s_loc[d] = 0.f;
  float csum = 0.f;

  for (int ii = 0; ii < IPW; ii += PF) {
#pragma unroll
    for (int p = 0; p < PF; ++p) {
      float scale = __half2float(__ushort_as_half(hbuf[p]));
      float u[16];
      {
        unsigned wd;
        wd = dbuf[p].x;
        u[0]  = (float)(wd & 0xffu);         u[1]  = (float)((wd >> 8) & 0xffu);
        u[2]  = (float)((wd >> 16) & 0xffu); u[3]  = (float)(wd >> 24);
        wd = dbuf[p].y;
        u[4]  = (float)(wd & 0xffu);         u[5]  = (float)((wd >> 8) & 0xffu);
        u[6]  = (float)((wd >> 16) & 0xffu); u[7]  = (float)(wd >> 24);
        wd = dbuf[p].z;
        u[8]  = (float)(wd & 0xffu);         u[9]  = (float)((wd >> 8) & 0xffu);
        u[10] = (float)((wd >> 16) & 0xffu); u[11] = (float)(wd >> 24);
        wd = dbuf[p].w;
        u[12] = (float)(wd & 0xffu);         u[13] = (float)((wd >> 8) & 0xffu);
        u[14] = (float)((wd >> 16) & 0xffu); u[15] = (float)(wd >> 24);
      }

      int ip = (i0 + ii + p + PF) & (I_ - 1);
      dbuf[p] = *(const uint4*)(base + (size_t)ip * K_);
      hbuf[p] = scb[(size_t)ip * N_];

      if (MODE == 0) {
#pragma unroll
        for (int d = 0; d < 16; ++d) s_loc[d] = fmaf(scale, u[d], s_loc[d]);
        csum += scale;
      } else {
        float dot = 0.f;
#pragma unroll
        for (int d = 0; d < 16; ++d) dot = fmaf(u[d], vsum[d], dot);
        float bl = scale * (dot - voff);
        float m = bl;
        m = fmaxf(m, __shfl_xor(m, 1));
        m = fmaxf(m, __shfl_xor(m, 2));
        m = fmaxf(m, __shfl_xor(m, 4));
        m = fmaxf(m, __shfl_xor(m, 8));
        m = fmaxf(m, __shfl_xor(m, 16));
        m = fmaxf(m, __shfl_xor(m, 32));
        float e = __expf(bl - m);
        float ss = e;
        ss += __shfl_xor(ss, 1);
        ss += __shfl_xor(ss, 2);
        ss += __shfl_xor(ss, 4);
        ss += __shfl_xor(ss, 8);
        ss += __shfl_xor(ss, 16);
        ss += __shfl_xor(ss, 32);
        float cs = __fdividef(e, ss) * scale;
#pragma unroll
        for (int d = 0; d < 16; ++d) s_loc[d] = fmaf(cs, u[d], s_loc[d]);
        csum += cs;
      }
    }
  }

#pragma unroll
  for (int d = 0; d < 16; ++d) s_loc[d] -= 128.0f * csum;
  if (MODE == 0) {
#pragma unroll
    for (int d = 0; d < 16; ++d) s_loc[d] *= (1.0f / 64.0f);
  }

  __shared__ float sred[4][64 * 17];
#pragma unroll
  for (int d = 0; d < 16; ++d) sred[wv][lane * 17 + d] = s_loc[d];
  __syncthreads();
#pragma unroll
  for (int e = 0; e < 4; ++e) {
    int idx = t * 4 + e;
    int n = idx >> 4, d = idx & 15;
    float val = sred[0][n*17+d] + sred[1][n*17+d] + sred[2][n*17+d] + sred[3][n*17+d];
    atomicAdd(&s_out[(size_t)b * K_ + idx], val);
  }

  // ---- fused squash tail (MODE 2 only): last block computes out = squash(s2+bias)
  if (MODE == 2) {
    __threadfence();                         // release our s_out atomics
    __shared__ unsigned last_blk;
    if (t == 0) last_blk = atomicAdd(ctr, 1u);
    __syncthreads();
    if (last_blk == 1023u) {                 // we are the last block
      __threadfence();                       // acquire all other blocks' s_out
      for (int idx = t; idx < (B_ * K_) / 4; idx += 256) {
        int b2 = idx >> 8;                   // batch
        int k0 = (idx & 255) * 4;            // 4 consecutive k; 4 lanes per n
        float4 s = *(const float4*)&s_out[(size_t)b2 * K_ + k0];
        float4 bb = *(const float4*)&bias[k0];
        s.x += bb.x; s.y += bb.y; s.z += bb.z; s.w += bb.w;
        float p = s.x * s.x + s.y * s.y + s.z * s.z + s.w * s.w;
        p += __shfl_xor(p, 1);
        p += __shfl_xor(p, 2);
        float n2 = p + 1e-7f;
        float nrm = sqrtf(n2);
        float f = nrm / (1.0f + n2);
        float4 o = {s.x * f, s.y * f, s.z * f, s.w * f};
        *(float4*)&out[(size_t)b2 * K_ + k0] = o;
      }
    }
  }
}

extern "C" void kernel_launch(void* const* d_in, const int* in_sizes, int n_in,
                              void* d_out, int out_size, void* d_ws, size_t ws_size,
                              hipStream_t stream) {
  const float* x    = (const float*)d_in[0];
  const float* W    = (const float*)d_in[1];
  const float* bias = (const float*)d_in[2];
  float* out = (float*)d_out;

  char* ws = (char*)d_ws;
  size_t off = 0;
  unsigned char*  uh = (unsigned char*)(ws + off);  off += (size_t)B_ * I_ * K_;      // 134 MB u8
  unsigned short* sc = (unsigned short*)(ws + off); off += (size_t)B_ * I_ * N_ * 2;  // 16.8 MB f16 scales
  float* s0 = (float*)(ws + off); off += (size_t)B_ * K_ * 4;
  float* s1 = (float*)(ws + off); off += (size_t)B_ * K_ * 4;
  float* s2 = (float*)(ws + off); off += (size_t)B_ * K_ * 4;
  unsigned* ctr = (unsigned*)(ws + off); off += 256;

  if (ws_size < off)
    fprintf(stderr, "ClassCapsule: ws_size=%zu < needed=%zu — expect corruption\n", ws_size, off);

  // project also zeroes s0..s2 + ctr — no memset dispatch
  project_k<<<dim3(I_ * 4), dim3(256), 0, stream>>>(x, W, uh, sc, s0, ctr);

  route_k<0><<<dim3(1024), dim3(256), 0, stream>>>(uh, sc, nullptr, nullptr, bias, s0, ctr, nullptr);
  route_k<1><<<dim3(1024), dim3(256), 0, stream>>>(uh, sc, s0, nullptr, bias, s1, ctr, nullptr);
  route_k<2><<<dim3(1024), dim3(256), 0, stream>>>(uh, sc, s0, s1, bias, s2, ctr, out);
}

// Round 25
// 158.751 us; speedup vs baseline: 1.7833x; 1.7833x over previous
//
#include <hip/hip_runtime.h>
#include <hip/hip_bf16.h>
#include <hip/hip_fp16.h>
#include <cstdio>

#define B_  64
#define I_  2048
#define J_  16
#define N_  64
#define D_  16
#define K_  1024   // N_*D_

using short8 = __attribute__((ext_vector_type(8))) short;
using f32x16 = __attribute__((ext_vector_type(16))) float;

#if __has_builtin(__builtin_amdgcn_cvt_pk_u8_f32)
#define CVTPK_U8(f, sel, old) (unsigned)__builtin_amdgcn_cvt_pk_u8_f32((f), (sel), (old))
#else
__device__ __forceinline__ unsigned cvtpk_u8_sw(float f, unsigned sel, unsigned old) {
  unsigned b = (unsigned)(int)f & 0xffu;
  unsigned sh = sel * 8u;
  return (old & ~(0xffu << sh)) | (b << sh);
}
#define CVTPK_U8(f, sel, old) cvtpk_u8_sw((f), (sel), (old))
#endif

__device__ __forceinline__ short8 pack_bf16x8(float a0, float a1, float a2, float a3,
                                              float a4, float a5, float a6, float a7) {
  __hip_bfloat162 p0 = __float22bfloat162_rn(float2{a0, a1});
  __hip_bfloat162 p1 = __float22bfloat162_rn(float2{a2, a3});
  __hip_bfloat162 p2 = __float22bfloat162_rn(float2{a4, a5});
  __hip_bfloat162 p3 = __float22bfloat162_rn(float2{a6, a7});
  union { unsigned u[4]; short8 s; } cv;
  cv.u[0] = *(unsigned*)&p0; cv.u[1] = *(unsigned*)&p1;
  cv.u[2] = *(unsigned*)&p2; cv.u[3] = *(unsigned*)&p3;
  return cv.s;
}

// ---------- projection via MFMA 32x32x16, ONE k-quarter per block ----------
// ROUND-22 kernel exactly (best measured total: 159.2 us).
// [round-23 lesson: lb(256,8) -> VGPR 32 -> spills (+115MB scratch traffic)]
// [round-24 lesson: fused squash tail's __threadfence() per block = L2 flush storm]
// Grid 8192: block = (i = bid>>2, ph = bid&3). LDS aliased 19.2 KB; pad-65 rows.
//   A frag: lane l = A[row=l&31][kappa=(l>>5)*8+e] -> W[j=kappa][k]
//   B frag: lane l = B[kappa=(l>>5)*8+e][col=l&31] -> x[b=col(+32)][j=kappa]
//   D frag: col=l&31 (b), row=(reg&3)+8*(reg>>2)+4*(l>>5)  [m74/m101-verified]
__global__ __launch_bounds__(256, 5) void project_k(const float* __restrict__ x,
                                                    const float* __restrict__ W,
                                                    unsigned char* __restrict__ uh,
                                                    unsigned short* __restrict__ sc,
                                                    float* __restrict__ s_zero) {
  const int i  = blockIdx.x >> 2;
  const int ph = blockIdx.x & 3;
  const int t  = threadIdx.x;
  const int l  = t & 63;
  const int wv = t >> 6;
  const int h  = l >> 5;
  const int lr = l & 31;

  __shared__ __align__(16) char smem[19200];
  unsigned short* lds_w   = (unsigned short*)smem;           // [256*20] 10240 B
  float*          lds_x   = (float*)(smem + 10240);          // [64*20]   5120 B
  unsigned*       out_lds = (unsigned*)smem;                 // [64*65]  16640 B (aliases stage)
  unsigned short* sc_lds  = (unsigned short*)(smem + 16640); // [64*20]   2560 B

  if (blockIdx.x < 768) s_zero[blockIdx.x * 256 + t] = 0.f;  // replaces memset

  {
    int b = t >> 2, q = t & 3;
    float4 v = ((const float4*)(x + ((size_t)b * I_ + i) * J_))[q];
    *(float4*)&lds_x[b * 20 + q * 4] = v;
  }
  {
    const float* wp = W + (size_t)i * (J_ * K_) + ph * 256;
    const int j0 = (t & 3) * 4;
    const int kg = t >> 2;
    float4 r0 = *(const float4*)(wp + (size_t)(j0 + 0) * K_ + kg * 4);
    float4 r1 = *(const float4*)(wp + (size_t)(j0 + 1) * K_ + kg * 4);
    float4 r2 = *(const float4*)(wp + (size_t)(j0 + 2) * K_ + kg * 4);
    float4 r3 = *(const float4*)(wp + (size_t)(j0 + 3) * K_ + kg * 4);
    const float* p0 = (const float*)&r0;
    const float* p1 = (const float*)&r1;
    const float* p2 = (const float*)&r2;
    const float* p3 = (const float*)&r3;
#pragma unroll
    for (int kk = 0; kk < 4; ++kk) {
      __hip_bfloat162 pA = __float22bfloat162_rn(float2{p0[kk], p1[kk]});
      __hip_bfloat162 pB = __float22bfloat162_rn(float2{p2[kk], p3[kk]});
      uint2 u; u.x = *(unsigned*)&pA; u.y = *(unsigned*)&pB;
      *(uint2*)&lds_w[(kg * 4 + kk) * 20 + j0] = u;
    }
  }
  __syncthreads();

  short8 xfrag;
  {
    int b = (wv & 1) * 32 + lr;
    const float* xp = &lds_x[b * 20 + h * 8];
    float4 f0 = *(const float4*)xp;
    float4 f1 = *(const float4*)(xp + 4);
    xfrag = pack_bf16x8(f0.x, f0.y, f0.z, f0.w, f1.x, f1.y, f1.z, f1.w);
  }

  const int b  = (wv & 1) * 32 + lr;
  const int kt_base = (wv >> 1) * 4;

  unsigned pkr[16];
  float    axr[8];

#pragma unroll
  for (int kk = 0; kk < 4; ++kk) {
    const int kt = kt_base + kk;
    const unsigned short* ap = &lds_w[(kt * 32 + lr) * 20 + h * 8];
    union { uint2 u2[2]; short8 s; } cv;
    cv.u2[0] = *(const uint2*)ap;
    cv.u2[1] = *(const uint2*)(ap + 4);
    f32x16 acc = {0.f, 0.f, 0.f, 0.f, 0.f, 0.f, 0.f, 0.f,
                  0.f, 0.f, 0.f, 0.f, 0.f, 0.f, 0.f, 0.f};
    acc = __builtin_amdgcn_mfma_f32_32x32x16_bf16(cv.s, xfrag, acc, 0, 0, 0);

#define QCAP(C8, CS) do {                                                       \
    float ax = fabsf(acc[(C8) + 0]);                                            \
    ax = fmaxf(ax, fabsf(acc[(C8) + 1]));                                       \
    ax = fmaxf(ax, fabsf(acc[(C8) + 2]));                                       \
    ax = fmaxf(ax, fabsf(acc[(C8) + 3]));                                       \
    ax = fmaxf(ax, fabsf(acc[(C8) + 4]));                                       \
    ax = fmaxf(ax, fabsf(acc[(C8) + 5]));                                       \
    ax = fmaxf(ax, fabsf(acc[(C8) + 6]));                                       \
    ax = fmaxf(ax, fabsf(acc[(C8) + 7]));                                       \
    ax = fmaxf(ax, __shfl_xor(ax, 32));                                         \
    float inv = __fdividef(127.0f, fmaxf(ax, 1e-30f));                          \
    unsigned pk0 = CVTPK_U8(rintf(fmaf(acc[(C8) + 0], inv, 128.f)), 0u, 0u);    \
    pk0 = CVTPK_U8(rintf(fmaf(acc[(C8) + 1], inv, 128.f)), 1u, pk0);            \
    pk0 = CVTPK_U8(rintf(fmaf(acc[(C8) + 2], inv, 128.f)), 2u, pk0);            \
    pk0 = CVTPK_U8(rintf(fmaf(acc[(C8) + 3], inv, 128.f)), 3u, pk0);            \
    unsigned pk1 = CVTPK_U8(rintf(fmaf(acc[(C8) + 4], inv, 128.f)), 0u, 0u);    \
    pk1 = CVTPK_U8(rintf(fmaf(acc[(C8) + 5], inv, 128.f)), 1u, pk1);            \
    pk1 = CVTPK_U8(rintf(fmaf(acc[(C8) + 6], inv, 128.f)), 2u, pk1);            \
    pk1 = CVTPK_U8(rintf(fmaf(acc[(C8) + 7], inv, 128.f)), 3u, pk1);            \
    pkr[kk * 4 + (CS) * 2 + 0] = pk0;                                           \
    pkr[kk * 4 + (CS) * 2 + 1] = pk1;                                           \
    axr[kk * 2 + (CS)] = ax;                                                    \
  } while (0)

    QCAP(0, 0);
    QCAP(8, 1);
#undef QCAP
  }
  __syncthreads();   // stage region dead; out region live

#pragma unroll
  for (int kk = 0; kk < 4; ++kk) {
    const int kt = kt_base + kk;
#pragma unroll
    for (int cs = 0; cs < 2; ++cs) {
      const int ibase = kt * 8 + cs * 4;
      out_lds[b * 65 + ibase + h]     = pkr[kk * 4 + cs * 2 + 0];
      out_lds[b * 65 + ibase + 2 + h] = pkr[kk * 4 + cs * 2 + 1];
      if (h == 0)
        sc_lds[b * 20 + kt * 2 + cs] =
            __half_as_ushort(__float2half_rn(axr[kk * 2 + cs] * (1.0f / 127.0f)));
    }
  }
  __syncthreads();

  {
    const int c = t & 15;
#pragma unroll
    for (int it = 0; it < 4; ++it) {
      int bf = (t >> 4) + it * 16;
      const unsigned* rp = &out_lds[bf * 65 + c * 4];
      uint4 v;
      v.x = rp[0]; v.y = rp[1]; v.z = rp[2]; v.w = rp[3];
      *(uint4*)(uh + (size_t)bf * I_ * K_ + (size_t)i * K_ + ph * 256 + c * 16) = v;
    }
    int b2 = t >> 2, n4 = (t & 3) * 4;
    uint2 sv = *(const uint2*)&sc_lds[b2 * 20 + n4];
    *(uint2*)(sc + (size_t)b2 * I_ * N_ + (size_t)i * N_ + ph * 16 + n4) = sv;
  }
}

// ---------- routing on u8 u_hat (e = q+128): lane = n; 16 B data + 2 B scale ----------
// (unchanged — proven, L3-resident)
template <int MODE>
__global__ __launch_bounds__(256, 4) void route_k(const unsigned char* __restrict__ uh,
                                                  const unsigned short* __restrict__ sc,
                                                  const float* __restrict__ sa,
                                                  const float* __restrict__ sb,
                                                  const float* __restrict__ bias,
                                                  float* __restrict__ s_out) {
  const int t    = threadIdx.x;
  const int lane = t & 63;            // = n
  const int wv   = t >> 6;            // 0..3
  const int b    = blockIdx.x >> 4;
  const int iw   = ((blockIdx.x & 15) << 2) + wv;
  const int i0   = iw * 32;

  float vsum[16];
  float voff = 0.f;
  if (MODE >= 1) {
    float bs[16];
#pragma unroll
    for (int q = 0; q < 4; ++q) {
      float4 bb4 = *(const float4*)&bias[lane * 16 + q * 4];
      bs[q*4+0] = bb4.x; bs[q*4+1] = bb4.y; bs[q*4+2] = bb4.z; bs[q*4+3] = bb4.w;
    }
    {
      float va[16], nn = 0.f;
#pragma unroll
      for (int q = 0; q < 4; ++q) {
        float4 tmp = *(const float4*)&sa[(size_t)b * K_ + lane * 16 + q * 4];
        va[q*4+0] = tmp.x + bs[q*4+0]; va[q*4+1] = tmp.y + bs[q*4+1];
        va[q*4+2] = tmp.z + bs[q*4+2]; va[q*4+3] = tmp.w + bs[q*4+3];
      }
#pragma unroll
      for (int d = 0; d < 16; ++d) nn += va[d] * va[d];
      float n2 = nn + 1e-7f;
      float f = sqrtf(n2) / (1.0f + n2);
#pragma unroll
      for (int d = 0; d < 16; ++d) vsum[d] = va[d] * f;
    }
    if (MODE == 2) {
      float vb[16], nn = 0.f;
#pragma unroll
      for (int q = 0; q < 4; ++q) {
        float4 tmp = *(const float4*)&sb[(size_t)b * K_ + lane * 16 + q * 4];
        vb[q*4+0] = tmp.x + bs[q*4+0]; vb[q*4+1] = tmp.y + bs[q*4+1];
        vb[q*4+2] = tmp.z + bs[q*4+2]; vb[q*4+3] = tmp.w + bs[q*4+3];
      }
#pragma unroll
      for (int d = 0; d < 16; ++d) nn += vb[d] * vb[d];
      float n2 = nn + 1e-7f;
      float f = sqrtf(n2) / (1.0f + n2);
#pragma unroll
      for (int d = 0; d < 16; ++d) vsum[d] += vb[d] * f;
    }
    float tv = 0.f;
#pragma unroll
    for (int d = 0; d < 16; ++d) tv += vsum[d];
    voff = 128.0f * tv;
  }

  constexpr int IPW = 32;
  constexpr int PF  = 4;

  const unsigned char*  base = uh + (size_t)b * I_ * K_ + lane * 16;
  const unsigned short* scb  = sc + (size_t)b * I_ * N_ + lane;

  uint4 dbuf[PF];
  unsigned short hbuf[PF];
#pragma unroll
  for (int p = 0; p < PF; ++p) {
    int ip = (i0 + p) & (I_ - 1);
    dbuf[p] = *(const uint4*)(base + (size_t)ip * K_);
    hbuf[p] = scb[(size_t)ip * N_];
  }

  float s_loc[16];
#pragma unroll
  for (int d = 0; d < 16; ++d) s_loc[d] = 0.f;
  float csum = 0.f;

  for (int ii = 0; ii < IPW; ii += PF) {
#pragma unroll
    for (int p = 0; p < PF; ++p) {
      float scale = __half2float(__ushort_as_half(hbuf[p]));
      float u[16];
      {
        unsigned wd;
        wd = dbuf[p].x;
        u[0]  = (float)(wd & 0xffu);         u[1]  = (float)((wd >> 8) & 0xffu);
        u[2]  = (float)((wd >> 16) & 0xffu); u[3]  = (float)(wd >> 24);
        wd = dbuf[p].y;
        u[4]  = (float)(wd & 0xffu);         u[5]  = (float)((wd >> 8) & 0xffu);
        u[6]  = (float)((wd >> 16) & 0xffu); u[7]  = (float)(wd >> 24);
        wd = dbuf[p].z;
        u[8]  = (float)(wd & 0xffu);         u[9]  = (float)((wd >> 8) & 0xffu);
        u[10] = (float)((wd >> 16) & 0xffu); u[11] = (float)(wd >> 24);
        wd = dbuf[p].w;
        u[12] = (float)(wd & 0xffu);         u[13] = (float)((wd >> 8) & 0xffu);
        u[14] = (float)((wd >> 16) & 0xffu); u[15] = (float)(wd >> 24);
      }

      int ip = (i0 + ii + p + PF) & (I_ - 1);
      dbuf[p] = *(const uint4*)(base + (size_t)ip * K_);
      hbuf[p] = scb[(size_t)ip * N_];

      if (MODE == 0) {
#pragma unroll
        for (int d = 0; d < 16; ++d) s_loc[d] = fmaf(scale, u[d], s_loc[d]);
        csum += scale;
      } else {
        float dot = 0.f;
#pragma unroll
        for (int d = 0; d < 16; ++d) dot = fmaf(u[d], vsum[d], dot);
        float bl = scale * (dot - voff);
        float m = bl;
        m = fmaxf(m, __shfl_xor(m, 1));
        m = fmaxf(m, __shfl_xor(m, 2));
        m = fmaxf(m, __shfl_xor(m, 4));
        m = fmaxf(m, __shfl_xor(m, 8));
        m = fmaxf(m, __shfl_xor(m, 16));
        m = fmaxf(m, __shfl_xor(m, 32));
        float e = __expf(bl - m);
        float ss = e;
        ss += __shfl_xor(ss, 1);
        ss += __shfl_xor(ss, 2);
        ss += __shfl_xor(ss, 4);
        ss += __shfl_xor(ss, 8);
        ss += __shfl_xor(ss, 16);
        ss += __shfl_xor(ss, 32);
        float cs = __fdividef(e, ss) * scale;
#pragma unroll
        for (int d = 0; d < 16; ++d) s_loc[d] = fmaf(cs, u[d], s_loc[d]);
        csum += cs;
      }
    }
  }

#pragma unroll
  for (int d = 0; d < 16; ++d) s_loc[d] -= 128.0f * csum;
  if (MODE == 0) {
#pragma unroll
    for (int d = 0; d < 16; ++d) s_loc[d] *= (1.0f / 64.0f);
  }

  __shared__ float sred[4][64 * 17];
#pragma unroll
  for (int d = 0; d < 16; ++d) sred[wv][lane * 17 + d] = s_loc[d];
  __syncthreads();
#pragma unroll
  for (int e = 0; e < 4; ++e) {
    int idx = t * 4 + e;
    int n = idx >> 4, d = idx & 15;
    float val = sred[0][n*17+d] + sred[1][n*17+d] + sred[2][n*17+d] + sred[3][n*17+d];
    atomicAdd(&s_out[(size_t)b * K_ + idx], val);
  }
}

// ---------- final squash ----------
__global__ __launch_bounds__(256) void squash_k(const float* __restrict__ s_in,
                                                const float* __restrict__ bias,
                                                float* __restrict__ v_out) {
  const int b = blockIdx.x, t = threadIdx.x, k0 = t * 4;
  float4 s = *(const float4*)&s_in[b * K_ + k0];
  float4 bb = *(const float4*)&bias[k0];
  s.x += bb.x; s.y += bb.y; s.z += bb.z; s.w += bb.w;
  float p = s.x * s.x + s.y * s.y + s.z * s.z + s.w * s.w;
  p += __shfl_xor(p, 1);
  p += __shfl_xor(p, 2);
  float n2 = p + 1e-7f;
  float nrm = sqrtf(n2);
  float f = nrm / (1.0f + n2);
  float4 o = {s.x * f, s.y * f, s.z * f, s.w * f};
  *(float4*)&v_out[b * K_ + k0] = o;
}

extern "C" void kernel_launch(void* const* d_in, const int* in_sizes, int n_in,
                              void* d_out, int out_size, void* d_ws, size_t ws_size,
                              hipStream_t stream) {
  const float* x    = (const float*)d_in[0];
  const float* W    = (const float*)d_in[1];
  const float* bias = (const float*)d_in[2];
  float* out = (float*)d_out;

  char* ws = (char*)d_ws;
  size_t off = 0;
  unsigned char*  uh = (unsigned char*)(ws + off);  off += (size_t)B_ * I_ * K_;      // 134 MB u8
  unsigned short* sc = (unsigned short*)(ws + off); off += (size_t)B_ * I_ * N_ * 2;  // 16.8 MB f16 scales
  float* s0 = (float*)(ws + off); off += (size_t)B_ * K_ * 4;
  float* s1 = (float*)(ws + off); off += (size_t)B_ * K_ * 4;
  float* s2 = (float*)(ws + off); off += (size_t)B_ * K_ * 4;

  if (ws_size < off)
    fprintf(stderr, "ClassCapsule: ws_size=%zu < needed=%zu — expect corruption\n", ws_size, off);

  // project also zeroes s0..s2 (first 768 blocks) — no memset dispatch
  project_k<<<dim3(I_ * 4), dim3(256), 0, stream>>>(x, W, uh, sc, s0);

  route_k<0><<<dim3(1024), dim3(256), 0, stream>>>(uh, sc, nullptr, nullptr, bias, s0);
  route_k<1><<<dim3(1024), dim3(256), 0, stream>>>(uh, sc, s0, nullptr, bias, s1);
  route_k<2><<<dim3(1024), dim3(256), 0, stream>>>(uh, sc, s0, s1, bias, s2);
  squash_k<<<dim3(B_), dim3(256), 0, stream>>>(s2, bias, out);
}